// Round 11
// baseline (214.709 us; speedup 1.0000x reference)
//
#include <hip/hip_runtime.h>

// CTC loss forward (sum), faithful to the JAX reference.
// T=2048, N=256, C=128, L=200, S=2L+1=401.
//
// 8 waves (512 threads) per sample, ONE state per lane: wave w owns states
// 64w..64w+63 (states >400 are dead and harmless). Each SIMD hosts 2 waves
// of the SAME sample at different pipeline skews -> they fill each other's
// dependency-chain and transcendental-latency bubbles (round 10 had 1
// wave/SIMD: 221cy/step at only 39% VALU issue).
//
// Per lane-step (log2 domain): al = lse3(al, h1, h2+pk) + K*sc, where
// h1 = state s-1 (DPP wave_shr:1), h2 = state s-2 (second chained DPP).
// lse3 uses max3/med3/min3 + "1+" trick: 2 exp2 + 1 log = 3 trans/step.
// Lane-0/1 halo injected via the DPP 'old' operand from the producer wave's
// top-two states, exchanged through bnd2[w][t][2] (written every step by
// lanes 62/63 via a cndmask'd dummy-address ds_write - no exec dance).
//
// Cross-wave protocol (proven rounds 4-10): strictly left->right, 16-step
// blocks, monotonic per-wave flags, consumer bulk-reads 32 boundary floats
// per block via 8x ds_read_b128 broadcast. Wave 0 never waits (dummy flag).
// Wave 7 computes dead states only - kept running for SIMD load balance.
// Emissions: direct global->register, 16-deep prefetch, 1 load/step/lane
// (per-lane class: even lanes blank=0, odd lanes their label).

#define TT 2048
#define NN 256
#define CC 128
#define LL 200

#define K_LOG2E 1.4426950408889634f
#define K_LN2   0.6931471805599453f
#define NEGB   (-1.44e30f)   /* -1e30 * log2(e) */
#define PEN    (-2.0e30f)    /* additive 'disallowed' penalty */
#define NC4    131072u       /* NN*CC*4 bytes: stride between time rows */

__device__ __forceinline__ float max3f(float a, float b, float c) {
    float r; asm("v_max3_f32 %0, %1, %2, %3" : "=v"(r) : "v"(a), "v"(b), "v"(c)); return r;
}
__device__ __forceinline__ float med3f(float a, float b, float c) {
    float r; asm("v_med3_f32 %0, %1, %2, %3" : "=v"(r) : "v"(a), "v"(b), "v"(c)); return r;
}
__device__ __forceinline__ float min3f(float a, float b, float c) {
    float r; asm("v_min3_f32 %0, %1, %2, %3" : "=v"(r) : "v"(a), "v"(b), "v"(c)); return r;
}

__global__ __launch_bounds__(512, 1)
void ctc_alpha(const float* __restrict__ pred,
               const int* __restrict__ target,
               const int* __restrict__ tlen,
               float* __restrict__ loss_ws)
{
    __shared__ float bnd2[8][TT][2];   // [w][t][0]=state 64w+62, [1]=64w+63 (after step t)
    __shared__ float dummyw[8][96];    // dead-write sink for lanes 0..61
    __shared__ int   flags[16];        // [0..7] = blocks completed; [8] = INT_MAX dummy

    const int tid  = threadIdx.x;
    const int wid  = tid >> 6;
    const int lane = tid & 63;
    const int n    = blockIdx.x;

    if (tid < 16) flags[tid] = (tid >= 8) ? 0x7fffffff : 0;

    // per-state constants. Reference quirk: starts[0]=0, starts[n>0]=tlen[n-1].
    const int start = (n == 0) ? 0 : tlen[n - 1];
    const int s     = (wid << 6) | lane;      // this lane's single state
    int cls = 0; float pk = PEN;              // blank class / skip disallowed
    if (s & 1) {
        const int j = s >> 1;
        if (j < LL) {
            cls = target[start + j];
            if (s >= 3 && cls != target[start + j - 1]) pk = 0.0f;  // skip allowed
        }
    }

    // ---- alpha_0 (log2 domain): only states 0,1 live ----
    float al = NEGB;
    if (s < 2) al = K_LOG2E * pred[n * CC + cls];   // s=0: cls=0; s=1: cls=lab
    if (lane >= 62) bnd2[wid][0][lane - 62] = al;   // t=0 boundary (NEGB everywhere)
    __syncthreads();   // flags + t=0 boundaries visible before any spin

    // ---- emission register pipeline, depth 16 (rows t..t+15 resident) ----
    const char* pc = (const char*)pred;
    uint32_t off = (uint32_t)(NN * CC + n * CC + cls) * 4u;   // row 1, this lane's class
    float sc[16];
#pragma unroll
    for (int ph = 0; ph < 16; ++ph) {                         // rows 1..16
        sc[ph] = *(const float*)(pc + off);  off += NC4;
    }

    volatile int* pflag = &flags[(wid == 0) ? 8 : (wid - 1)];
    volatile int* mflag = &flags[wid];
    int fval = *pflag;

    const float4* bq = (const float4*)&bnd2[(wid == 0) ? 0 : (wid - 1)][0][0];
    float* const  wreal = &bnd2[wid][0][0];
    float* const  wdum  = &dummyw[wid][lane];
    const bool    iswr  = (lane >= 62);
    const int     wofs  = lane - 62;            // used only when iswr

    float hi[16], lo[16];
    // Boundaries for block B: entries t = 16B .. 16B+15 (alpha at t-1 for step t).
#define LOAD_B(B)                                                              \
    if (wid) {                                                                 \
        const float4* q = bq + (B) * 8;                                        \
        _Pragma("unroll")                                                      \
        for (int i = 0; i < 8; ++i) {                                          \
            const float4 v = q[i];                                             \
            lo[2*i] = v.x; hi[2*i] = v.y; lo[2*i+1] = v.z; hi[2*i+1] = v.w;    \
        }                                                                      \
    } else {                                                                   \
        _Pragma("unroll")                                                      \
        for (int i = 0; i < 16; ++i) { hi[i] = PEN; lo[i] = PEN; }             \
    }

    // One step, t = TBASE+1+PH. h1 = state s-1 (DPP shr1, lane0 <- hi[PH]);
    // h2 = state s-2 (chained DPP shr1, lane0 <- lo[PH], lane1 <- hi[PH]).
#define CTC_STEP(PH, PREF)                                                     \
    {                                                                          \
        const int h1i = __builtin_amdgcn_update_dpp(                           \
            __float_as_int(hi[PH]), __float_as_int(al), 0x138, 0xf, 0xf, false); \
        const int h2i = __builtin_amdgcn_update_dpp(                           \
            __float_as_int(lo[PH]), h1i, 0x138, 0xf, 0xf, false);              \
        const float h1 = __int_as_float(h1i);                                  \
        const float h2 = __int_as_float(h2i) + pk;                             \
        const float M  = max3f(al, h1, h2);                                    \
        const float md = med3f(al, h1, h2);                                    \
        const float lw = min3f(al, h1, h2);                                    \
        const float e  = 1.0f + __builtin_amdgcn_exp2f(md - M)                 \
                              + __builtin_amdgcn_exp2f(lw - M);                \
        al = fmaxf(fmaf(K_LOG2E, sc[PH], M + __builtin_amdgcn_logf(e)), NEGB); \
        wp[2 * (PH)] = al;                                                     \
        if (PREF) { sc[PH] = *(const float*)(pc + off);  off += NC4; }         \
    }

    // main: blocks b=0..125 cover t=1..2016, prefetch rows 17..2032
    for (int b = 0; b < 126; ++b) {
        const int need = b + 1;
        if (fval < need) { do { fval = *pflag; } while (fval < need); }
        asm volatile("" ::: "memory");
        LOAD_B(b)
        const int tb = 16 * b;
        float* wp = iswr ? (wreal + (tb + 1) * 2 + wofs) : wdum;
        CTC_STEP( 0, 1) CTC_STEP( 1, 1) CTC_STEP( 2, 1) CTC_STEP( 3, 1)
        CTC_STEP( 4, 1) CTC_STEP( 5, 1) CTC_STEP( 6, 1) CTC_STEP( 7, 1)
        CTC_STEP( 8, 1) CTC_STEP( 9, 1) CTC_STEP(10, 1) CTC_STEP(11, 1)
        CTC_STEP(12, 1) CTC_STEP(13, 1) CTC_STEP(14, 1) CTC_STEP(15, 1)
        asm volatile("" ::: "memory");                // bnd writes before flag post
        if (lane == 0) *mflag = b + 1;
        fval = *pflag;                                // refresh; checked next block
    }

    // block 126: t=2017..2032; prefetch rows 2033..2047 (last step: none)
    {
        if (fval < 127) { do { fval = *pflag; } while (fval < 127); }
        asm volatile("" ::: "memory");
        LOAD_B(126)
        float* wp = iswr ? (wreal + 2017 * 2 + wofs) : wdum;
        CTC_STEP( 0, 1) CTC_STEP( 1, 1) CTC_STEP( 2, 1) CTC_STEP( 3, 1)
        CTC_STEP( 4, 1) CTC_STEP( 5, 1) CTC_STEP( 6, 1) CTC_STEP( 7, 1)
        CTC_STEP( 8, 1) CTC_STEP( 9, 1) CTC_STEP(10, 1) CTC_STEP(11, 1)
        CTC_STEP(12, 1) CTC_STEP(13, 1) CTC_STEP(14, 1) CTC_STEP(15, 0)
        asm volatile("" ::: "memory");
        if (lane == 0) *mflag = 127;
        fval = *pflag;
    }

    // tail block 127: t=2033..2047 (15 steps), uses sc[0..14]=rows 2033..2047
    {
        if (fval < 128) { do { fval = *pflag; } while (fval < 128); }
        asm volatile("" ::: "memory");
        LOAD_B(127)
        float* wp = iswr ? (wreal + 2033 * 2 + wofs) : wdum;
        CTC_STEP( 0, 0) CTC_STEP( 1, 0) CTC_STEP( 2, 0) CTC_STEP( 3, 0)
        CTC_STEP( 4, 0) CTC_STEP( 5, 0) CTC_STEP( 6, 0) CTC_STEP( 7, 0)
        CTC_STEP( 8, 0) CTC_STEP( 9, 0) CTC_STEP(10, 0) CTC_STEP(11, 0)
        CTC_STEP(12, 0) CTC_STEP(13, 0) CTC_STEP(14, 0)
        asm volatile("" ::: "memory");
        if (lane == 0) *mflag = 128;                  // unblocks consumers' tails
    }
#undef CTC_STEP
#undef LOAD_B

    // loss: states 399, 400 live in wave 6 lanes 15, 16
    const float A = __shfl(al, 15, 64);
    const float B = __shfl(al, 16, 64);
    if (wid == 6 && lane == 0) {
        const float m  = fmaxf(A, B);
        const float ls = m + __builtin_amdgcn_logf(
            __builtin_amdgcn_exp2f(A - m) + __builtin_amdgcn_exp2f(B - m));
        loss_ws[n] = -ls * K_LN2;   // back to natural log
    }
}

__global__ void ctc_reduce(const float* __restrict__ ws, float* __restrict__ out)
{
    const int tid = threadIdx.x;   // 256 threads, 4 waves
    float v = ws[tid];
    v += __shfl_down(v, 32);
    v += __shfl_down(v, 16);
    v += __shfl_down(v, 8);
    v += __shfl_down(v, 4);
    v += __shfl_down(v, 2);
    v += __shfl_down(v, 1);
    __shared__ float p[4];
    if ((tid & 63) == 0) p[tid >> 6] = v;
    __syncthreads();
    if (tid == 0) out[0] = (p[0] + p[1]) + (p[2] + p[3]);
}

extern "C" void kernel_launch(void* const* d_in, const int* in_sizes, int n_in,
                              void* d_out, int out_size, void* d_ws, size_t ws_size,
                              hipStream_t stream)
{
    const float* pred   = (const float*)d_in[0];
    const int*   target = (const int*)d_in[1];
    // d_in[2] = input_length: unused by the reference computation
    const int*   tlen   = (const int*)d_in[3];
    float* ws = (float*)d_ws;

    ctc_alpha<<<NN, 512, 0, stream>>>(pred, target, tlen, ws);
    ctc_reduce<<<1, NN, 0, stream>>>(ws, (float*)d_out);
}

// Round 12
// 151.962 us; speedup vs baseline: 1.4129x; 1.4129x over previous
//
#include <hip/hip_runtime.h>

// CTC loss forward (sum), faithful to the JAX reference.
// T=2048, N=256, C=128, L=200, S=2L+1=401.
//
// Round-10 structure (best valid, 188.8us): one workgroup (4 waves) per
// sample, LOG2 domain, wave w owns states 128w..128w+127, 2/lane
// (s0=2idx blank, s1=2idx+1 label). Intra-wave halo via DPP wave_shr:1
// (old operand injects the cross-wave boundary). Cross-wave left->right
// only, 16-step blocks, monotonic per-wave flags. Wave 0 never waits.
// Emissions: direct global->register, 16-deep prefetch; blank-score offset
// kept in an OPAQUE VGPR so it cannot be scalarized to s_load (the round-6
// stall). Shared-frame lse: M=max3(al1,al0,h1) frames both state updates.
//
// Round-12 deltas vs round 10 (r11 showed adding waves = more issue = slower;
// instead remove r10's exposed latencies):
//  1. DOUBLE-BUFFERED boundary prefetch: block b prefetches block b+1's 16
//     boundaries (spin flag>=b+2, ping-pong register sets, static indexing).
//     r10 exposed ~120cy of LDS latency at every block head.
//  2. BATCHED boundary writes: bw[PH]=al1 (v_mov) per step + lane-63 burst
//     of 4x ds_write_b128 at block end (protocol-identical: flag posts after
//     the burst). Boundary layout blk[w][b][16] -> 16B-aligned reads/writes;
//     block-crossing value rides in the bprev register.
//  3. fmax NEGB clamps removed: fp32 absorption pins dead states at ~NEGB
//     (|NEGB| ulp ~1.5e23 >> per-step drift); exp2(-huge)=0, log2([1,3])
//     finite -> no inf/NaN path.

#define TT 2048
#define NN 256
#define CC 128
#define LL 200

#define K_LOG2E 1.4426950408889634f
#define K_LN2   0.6931471805599453f
#define NEGB   (-1.44e30f)   /* -1e30 * log2(e) */
#define PEN    (-2.0e30f)    /* 'disallowed' halo for wave 0 */
#define NC4    131072u       /* NN*CC*4 bytes: stride between time rows */

__device__ __forceinline__ float max3f(float a, float b, float c) {
    float r; asm("v_max3_f32 %0, %1, %2, %3" : "=v"(r) : "v"(a), "v"(b), "v"(c)); return r;
}

__global__ __launch_bounds__(256, 1)
void ctc_alpha(const float* __restrict__ pred,
               const int* __restrict__ target,
               const int* __restrict__ tlen,
               float* __restrict__ loss_ws)
{
    // [w][b][k]: boundary state 128w+127 AFTER step 16b+1+k. Row 4 = PEN
    // (wave 0's virtual producer). 16B-aligned blocks for float4 access.
    __shared__ float blk[5][128][16];
    __shared__ int   flags[8];     // [w]=blocks completed; [7]=INT_MAX dummy

    const int tid  = threadIdx.x;
    const int wid  = tid >> 6;
    const int lane = tid & 63;
    const int n    = blockIdx.x;

    if (tid < 8) flags[tid] = (tid >= 4) ? 0x7fffffff : 0;
    for (int i = tid; i < 128 * 16; i += 256) ((float*)blk[4])[i] = PEN;

    // per-state constants. Reference quirk: starts[0]=0, starts[n>0]=tlen[n-1].
    const int start = (n == 0) ? 0 : tlen[n - 1];
    const int idx   = (wid << 6) | lane;     // s0 = 2*idx (blank), s1 = 2*idx+1 (label)
    int lab1 = 0; float msk1 = 0.0f;
    if (idx < LL) {
        lab1 = target[start + idx];
        if (idx >= 1 && lab1 != target[start + idx - 1]) msk1 = 1.0f;  // skip allowed
    }

    // ---- alpha_0 (log2 domain): only states 0,1 (idx==0) live ----
    float al0, al1;
    {
        const float eB = pred[n * CC];
        const float eL = pred[n * CC + lab1];
        al0 = (idx == 0) ? K_LOG2E * eB : NEGB;
        al1 = (idx == 0) ? K_LOG2E * eL : NEGB;
    }
    __syncthreads();   // flags + PEN row visible before any spin

    // ---- emission register pipeline, depth 16 (rows t..t+15 resident) ----
    const char* pc = (const char*)pred;
    uint32_t offB = (uint32_t)(NN * CC + n * CC) * 4u;         // row 1, class 0
    uint32_t offL = offB + (uint32_t)lab1 * 4u;                // row 1, class lab1
    asm volatile("" : "+v"(offB));   // opaque: forbid s_load scalarization
    float scB[16], scL[16];
#pragma unroll
    for (int ph = 0; ph < 16; ++ph) {                          // rows 1..16
        scB[ph] = *(const float*)(pc + offB);  offB += NC4;
        scL[ph] = *(const float*)(pc + offL);  offL += NC4;
    }

    float (* const blkC)[16] = blk[(wid == 0) ? 4 : (wid - 1)];
    float (* const blkW)[16] = blk[wid];
    volatile int* pflag = &flags[(wid == 0) ? 7 : (wid - 1)];
    volatile int* mflag = &flags[wid];
    int fval = *pflag;

    float bndA[16], bndB[16], bw[16];
    float bprev = (wid == 0) ? PEN : NEGB;    // boundary after step 0 (alpha0)

#define LOAD_BLK(DST, B)                                                       \
    {                                                                          \
        const float4* q = (const float4*)&blkC[B][0];                          \
        const float4 v0 = q[0], v1 = q[1], v2 = q[2], v3 = q[3];               \
        DST[0]=v0.x;  DST[1]=v0.y;  DST[2]=v0.z;  DST[3]=v0.w;                 \
        DST[4]=v1.x;  DST[5]=v1.y;  DST[6]=v1.z;  DST[7]=v1.w;                 \
        DST[8]=v2.x;  DST[9]=v2.y;  DST[10]=v2.z; DST[11]=v2.w;                \
        DST[12]=v3.x; DST[13]=v3.y; DST[14]=v3.z; DST[15]=v3.w;                \
    }

#define STORE_BLK(B)                                                           \
    if (lane == 63) {                                                          \
        float4* d = (float4*)&blkW[B][0];                                      \
        d[0] = make_float4(bw[0],  bw[1],  bw[2],  bw[3]);                     \
        d[1] = make_float4(bw[4],  bw[5],  bw[6],  bw[7]);                     \
        d[2] = make_float4(bw[8],  bw[9],  bw[10], bw[11]);                    \
        d[3] = make_float4(bw[12], bw[13], bw[14], bw[15]);                    \
    }

    // One step, PH = 0..15 of a block. Halo h1 = prev lane's al1; lane0 <-
    // boundary (bprev for PH=0, else BV[PH-1]) via update_dpp old operand
    // (wave_shr:1 = 0x138). Shared frame M serves both state updates.
#define CTC_STEP(PH, BV, PREF)                                                 \
    {                                                                          \
        const float hold = ((PH) == 0) ? bprev : BV[((PH) + 15) & 15];         \
        const int h1i = __builtin_amdgcn_update_dpp(                           \
            __float_as_int(hold), __float_as_int(al1), 0x138, 0xf, 0xf, false);\
        const float h1 = __int_as_float(h1i);                                  \
        const float M  = max3f(al1, al0, h1);                                  \
        const float e1 = __builtin_amdgcn_exp2f(al1 - M);                      \
        const float e0 = __builtin_amdgcn_exp2f(al0 - M);                      \
        const float eh = __builtin_amdgcn_exp2f(h1 - M);                       \
        const float s1 = fmaf(eh, msk1, e1 + e0);                              \
        const float s0 = e0 + eh;                                              \
        al1 = fmaf(K_LOG2E, scL[PH], M + __builtin_amdgcn_logf(s1));           \
        al0 = fmaf(K_LOG2E, scB[PH], M + __builtin_amdgcn_logf(s0));           \
        bw[PH] = al1;                                                          \
        if (PREF) {                                                            \
            scB[PH] = *(const float*)(pc + offB);  offB += NC4;                \
            scL[PH] = *(const float*)(pc + offL);  offL += NC4;                \
        }                                                                      \
    }

    // Block b: use BUSE (prefetched last block), prefetch block b+1 -> BPRE.
#define RUN_BLOCK(B, BUSE, BPRE, NEED, LASTPREF)                               \
    {                                                                          \
        const int need_ = (NEED);                                              \
        if (fval < need_) { do { fval = *pflag; } while (fval < need_); }      \
        asm volatile("" ::: "memory");                                         \
        LOAD_BLK(BPRE, (B) + 1)                                                \
        CTC_STEP( 0, BUSE, 1) CTC_STEP( 1, BUSE, 1) CTC_STEP( 2, BUSE, 1)      \
        CTC_STEP( 3, BUSE, 1) CTC_STEP( 4, BUSE, 1) CTC_STEP( 5, BUSE, 1)      \
        CTC_STEP( 6, BUSE, 1) CTC_STEP( 7, BUSE, 1) CTC_STEP( 8, BUSE, 1)      \
        CTC_STEP( 9, BUSE, 1) CTC_STEP(10, BUSE, 1) CTC_STEP(11, BUSE, 1)      \
        CTC_STEP(12, BUSE, 1) CTC_STEP(13, BUSE, 1) CTC_STEP(14, BUSE, 1)      \
        CTC_STEP(15, BUSE, LASTPREF)                                           \
        STORE_BLK(B)                                                           \
        asm volatile("" ::: "memory");       /* burst before flag post */      \
        if (lane == 0) *mflag = (B) + 1;                                       \
        bprev = BUSE[15];                                                      \
        fval = *pflag;                                                         \
    }

    // prologue: block 0's boundaries (written by producer's block 0)
    if (fval < 1) { do { fval = *pflag; } while (fval < 1); }
    asm volatile("" ::: "memory");
    LOAD_BLK(bndA, 0)

    // main: blocks 0..125 (t = 1..2016), ping-pong A/B, prefetch b+1
    for (int bb = 0; bb < 63; ++bb) {
        RUN_BLOCK(2 * bb,     bndA, bndB, 2 * bb + 2, 1)
        RUN_BLOCK(2 * bb + 1, bndB, bndA, 2 * bb + 3, 1)
    }

    // block 126 (t=2017..2032): prefetch block 127 (needs producer DONE=128);
    // emission prefetch rows 2033..2047 (step 15: none).
    RUN_BLOCK(126, bndA, bndB, 128, 0)

    // tail block 127: t = 2033..2047 (15 steps), data already in bndB.
    {
        asm volatile("" ::: "memory");
        CTC_STEP( 0, bndB, 0) CTC_STEP( 1, bndB, 0) CTC_STEP( 2, bndB, 0)
        CTC_STEP( 3, bndB, 0) CTC_STEP( 4, bndB, 0) CTC_STEP( 5, bndB, 0)
        CTC_STEP( 6, bndB, 0) CTC_STEP( 7, bndB, 0) CTC_STEP( 8, bndB, 0)
        CTC_STEP( 9, bndB, 0) CTC_STEP(10, bndB, 0) CTC_STEP(11, bndB, 0)
        CTC_STEP(12, bndB, 0) CTC_STEP(13, bndB, 0) CTC_STEP(14, bndB, 0)
        STORE_BLK(127)                      // slots 14,15 unused by consumers
        asm volatile("" ::: "memory");
        if (lane == 0) *mflag = 128;
    }
#undef CTC_STEP
#undef RUN_BLOCK
#undef LOAD_BLK
#undef STORE_BLK

    // loss: states 399 (wave3 lane7 al1) and 400 (wave3 lane8 al0)
    const float A = __shfl(al1, 7, 64);
    const float B = __shfl(al0, 8, 64);
    if (wid == 3 && lane == 0) {
        const float m  = fmaxf(A, B);
        const float ls = m + __builtin_amdgcn_logf(
            __builtin_amdgcn_exp2f(A - m) + __builtin_amdgcn_exp2f(B - m));
        loss_ws[n] = -ls * K_LN2;   // back to natural log
    }
}

__global__ void ctc_reduce(const float* __restrict__ ws, float* __restrict__ out)
{
    const int tid = threadIdx.x;   // 256 threads, 4 waves
    float v = ws[tid];
    v += __shfl_down(v, 32);
    v += __shfl_down(v, 16);
    v += __shfl_down(v, 8);
    v += __shfl_down(v, 4);
    v += __shfl_down(v, 2);
    v += __shfl_down(v, 1);
    __shared__ float p[4];
    if ((tid & 63) == 0) p[tid >> 6] = v;
    __syncthreads();
    if (tid == 0) out[0] = (p[0] + p[1]) + (p[2] + p[3]);
}

extern "C" void kernel_launch(void* const* d_in, const int* in_sizes, int n_in,
                              void* d_out, int out_size, void* d_ws, size_t ws_size,
                              hipStream_t stream)
{
    const float* pred   = (const float*)d_in[0];
    const int*   target = (const int*)d_in[1];
    // d_in[2] = input_length: unused by the reference computation
    const int*   tlen   = (const int*)d_in[3];
    float* ws = (float*)d_ws;

    ctc_alpha<<<NN, 256, 0, stream>>>(pred, target, tlen, ws);
    ctc_reduce<<<1, NN, 0, stream>>>(ws, (float*)d_out);
}

// Round 13
// 150.974 us; speedup vs baseline: 1.4222x; 1.0065x over previous
//
#include <hip/hip_runtime.h>

// CTC loss forward (sum), faithful to the JAX reference.
// T=2048, N=256, C=128, L=200, S=2L+1=401.
//
// Round-12 structure (proven, 152us): one workgroup (4 waves) per sample,
// LOG2 domain, wave w owns states 128w..128w+127, 2/lane (s0=2idx blank,
// s1=2idx+1 label). Intra-wave halo via DPP wave_shr:1 (old operand injects
// the cross-wave boundary). Cross-wave left->right only, 16-step blocks,
// monotonic per-wave flags, double-buffered boundary prefetch (block b
// prefetches b+1's 16 boundaries), batched lane-63 boundary writes
// (4x ds_write_b128 per block). Wave 0 never waits.
//
// Round-13 deltas vs round 12 (issue/chain trims, zero structural change):
//  1. SGPR-base addressing: emission row pointer pcRow is UNIFORM and
//     advanced by SALU (free pipe); per-lane class byte-offsets live in
//     opaque VGPRs (vB kept opaque so the row-uniform blank load cannot be
//     scalarized to s_load - the round-6 stall). Removes 2 v_add/step.
//  2. Chain reassociation: b1 = fmaf(K,scL,M) issues OFF-chain right after
//     max3; al1 = b1 + log2(s1) leaves only one add after the log on the
//     serial al1->al1 cycle (was add+fma). Same op count, shorter chain.

#define TT 2048
#define NN 256
#define CC 128
#define LL 200

#define K_LOG2E 1.4426950408889634f
#define K_LN2   0.6931471805599453f
#define NEGB   (-1.44e30f)   /* -1e30 * log2(e) */
#define PEN    (-2.0e30f)    /* 'disallowed' halo for wave 0 */
#define NC4    131072u       /* NN*CC*4 bytes: stride between time rows */

__device__ __forceinline__ float max3f(float a, float b, float c) {
    float r; asm("v_max3_f32 %0, %1, %2, %3" : "=v"(r) : "v"(a), "v"(b), "v"(c)); return r;
}

__global__ __launch_bounds__(256, 1)
void ctc_alpha(const float* __restrict__ pred,
               const int* __restrict__ target,
               const int* __restrict__ tlen,
               float* __restrict__ loss_ws)
{
    // [w][b][k]: boundary state 128w+127 AFTER step 16b+1+k. Row 4 = PEN
    // (wave 0's virtual producer). 16B-aligned blocks for float4 access.
    __shared__ float blk[5][128][16];
    __shared__ int   flags[8];     // [w]=blocks completed; [7]=INT_MAX dummy

    const int tid  = threadIdx.x;
    const int wid  = tid >> 6;
    const int lane = tid & 63;
    const int n    = blockIdx.x;

    if (tid < 8) flags[tid] = (tid >= 4) ? 0x7fffffff : 0;
    for (int i = tid; i < 128 * 16; i += 256) ((float*)blk[4])[i] = PEN;

    // per-state constants. Reference quirk: starts[0]=0, starts[n>0]=tlen[n-1].
    const int start = (n == 0) ? 0 : tlen[n - 1];
    const int idx   = (wid << 6) | lane;     // s0 = 2*idx (blank), s1 = 2*idx+1 (label)
    int lab1 = 0; float msk1 = 0.0f;
    if (idx < LL) {
        lab1 = target[start + idx];
        if (idx >= 1 && lab1 != target[start + idx - 1]) msk1 = 1.0f;  // skip allowed
    }

    // ---- alpha_0 (log2 domain): only states 0,1 (idx==0) live ----
    float al0, al1;
    {
        const float eB = pred[n * CC];
        const float eL = pred[n * CC + lab1];
        al0 = (idx == 0) ? K_LOG2E * eB : NEGB;
        al1 = (idx == 0) ? K_LOG2E * eL : NEGB;
    }
    __syncthreads();   // flags + PEN row visible before any spin

    // ---- emission pipeline, depth 16: uniform row pointer (SALU-advanced)
    //      + per-lane class byte-offsets in opaque VGPRs (stay VMEM).
    const char* pcRow = (const char*)pred + (size_t)(NN * CC + n * CC) * 4u;  // row 1
    uint32_t vB = 0u;                         // blank class byte-offset
    uint32_t vL = (uint32_t)lab1 * 4u;        // label class byte-offset
    asm volatile("" : "+v"(vB), "+v"(vL));    // opaque: forbid s_load scalarization
    float scB[16], scL[16];
#pragma unroll
    for (int ph = 0; ph < 16; ++ph) {                          // rows 1..16
        scB[ph] = *(const float*)(pcRow + vB);
        scL[ph] = *(const float*)(pcRow + vL);
        pcRow += NC4;
    }

    float (* const blkC)[16] = blk[(wid == 0) ? 4 : (wid - 1)];
    float (* const blkW)[16] = blk[wid];
    volatile int* pflag = &flags[(wid == 0) ? 7 : (wid - 1)];
    volatile int* mflag = &flags[wid];
    int fval = *pflag;

    float bndA[16], bndB[16], bw[16];
    float bprev = (wid == 0) ? PEN : NEGB;    // boundary after step 0 (alpha0)

#define LOAD_BLK(DST, B)                                                       \
    {                                                                          \
        const float4* q = (const float4*)&blkC[B][0];                          \
        const float4 v0 = q[0], v1 = q[1], v2 = q[2], v3 = q[3];               \
        DST[0]=v0.x;  DST[1]=v0.y;  DST[2]=v0.z;  DST[3]=v0.w;                 \
        DST[4]=v1.x;  DST[5]=v1.y;  DST[6]=v1.z;  DST[7]=v1.w;                 \
        DST[8]=v2.x;  DST[9]=v2.y;  DST[10]=v2.z; DST[11]=v2.w;                \
        DST[12]=v3.x; DST[13]=v3.y; DST[14]=v3.z; DST[15]=v3.w;                \
    }

#define STORE_BLK(B)                                                           \
    if (lane == 63) {                                                          \
        float4* d = (float4*)&blkW[B][0];                                      \
        d[0] = make_float4(bw[0],  bw[1],  bw[2],  bw[3]);                     \
        d[1] = make_float4(bw[4],  bw[5],  bw[6],  bw[7]);                     \
        d[2] = make_float4(bw[8],  bw[9],  bw[10], bw[11]);                    \
        d[3] = make_float4(bw[12], bw[13], bw[14], bw[15]);                    \
    }

    // One step, PH = 0..15 of a block. Halo h1 = prev lane's al1; lane0 <-
    // boundary (bprev for PH=0, else BV[PH-1]) via update_dpp old operand
    // (wave_shr:1 = 0x138). Shared frame M; b1/b0 = M + K*sc computed
    // OFF-chain (right after max3) so only one add follows each log.
#define CTC_STEP(PH, BV, PREF)                                                 \
    {                                                                          \
        const float hold = ((PH) == 0) ? bprev : BV[((PH) + 15) & 15];         \
        const int h1i = __builtin_amdgcn_update_dpp(                           \
            __float_as_int(hold), __float_as_int(al1), 0x138, 0xf, 0xf, false);\
        const float h1 = __int_as_float(h1i);                                  \
        const float M  = max3f(al1, al0, h1);                                  \
        const float b1 = fmaf(K_LOG2E, scL[PH], M);                            \
        const float b0 = fmaf(K_LOG2E, scB[PH], M);                            \
        const float e1 = __builtin_amdgcn_exp2f(al1 - M);                      \
        const float e0 = __builtin_amdgcn_exp2f(al0 - M);                      \
        const float eh = __builtin_amdgcn_exp2f(h1 - M);                       \
        const float s1 = fmaf(eh, msk1, e1 + e0);                              \
        const float s0 = e0 + eh;                                              \
        al1 = b1 + __builtin_amdgcn_logf(s1);                                  \
        al0 = b0 + __builtin_amdgcn_logf(s0);                                  \
        bw[PH] = al1;                                                          \
        if (PREF) {                                                            \
            scB[PH] = *(const float*)(pcRow + vB);                             \
            scL[PH] = *(const float*)(pcRow + vL);                             \
            pcRow += NC4;                                                      \
        }                                                                      \
    }

    // Block b: use BUSE (prefetched last block), prefetch block b+1 -> BPRE.
#define RUN_BLOCK(B, BUSE, BPRE, NEED, LASTPREF)                               \
    {                                                                          \
        const int need_ = (NEED);                                              \
        if (fval < need_) { do { fval = *pflag; } while (fval < need_); }      \
        asm volatile("" ::: "memory");                                         \
        LOAD_BLK(BPRE, (B) + 1)                                                \
        CTC_STEP( 0, BUSE, 1) CTC_STEP( 1, BUSE, 1) CTC_STEP( 2, BUSE, 1)      \
        CTC_STEP( 3, BUSE, 1) CTC_STEP( 4, BUSE, 1) CTC_STEP( 5, BUSE, 1)      \
        CTC_STEP( 6, BUSE, 1) CTC_STEP( 7, BUSE, 1) CTC_STEP( 8, BUSE, 1)      \
        CTC_STEP( 9, BUSE, 1) CTC_STEP(10, BUSE, 1) CTC_STEP(11, BUSE, 1)      \
        CTC_STEP(12, BUSE, 1) CTC_STEP(13, BUSE, 1) CTC_STEP(14, BUSE, 1)      \
        CTC_STEP(15, BUSE, LASTPREF)                                           \
        STORE_BLK(B)                                                           \
        asm volatile("" ::: "memory");       /* burst before flag post */      \
        if (lane == 0) *mflag = (B) + 1;                                       \
        bprev = BUSE[15];                                                      \
        fval = *pflag;                                                         \
    }

    // prologue: block 0's boundaries (written by producer's block 0)
    if (fval < 1) { do { fval = *pflag; } while (fval < 1); }
    asm volatile("" ::: "memory");
    LOAD_BLK(bndA, 0)

    // main: blocks 0..125 (t = 1..2016), ping-pong A/B, prefetch b+1
    for (int bb = 0; bb < 63; ++bb) {
        RUN_BLOCK(2 * bb,     bndA, bndB, 2 * bb + 2, 1)
        RUN_BLOCK(2 * bb + 1, bndB, bndA, 2 * bb + 3, 1)
    }

    // block 126 (t=2017..2032): prefetch block 127 (needs producer DONE=128);
    // emission prefetch rows 2033..2047 (step 15: none).
    RUN_BLOCK(126, bndA, bndB, 128, 0)

    // tail block 127: t = 2033..2047 (15 steps), data already in bndB.
    {
        asm volatile("" ::: "memory");
        CTC_STEP( 0, bndB, 0) CTC_STEP( 1, bndB, 0) CTC_STEP( 2, bndB, 0)
        CTC_STEP( 3, bndB, 0) CTC_STEP( 4, bndB, 0) CTC_STEP( 5, bndB, 0)
        CTC_STEP( 6, bndB, 0) CTC_STEP( 7, bndB, 0) CTC_STEP( 8, bndB, 0)
        CTC_STEP( 9, bndB, 0) CTC_STEP(10, bndB, 0) CTC_STEP(11, bndB, 0)
        CTC_STEP(12, bndB, 0) CTC_STEP(13, bndB, 0) CTC_STEP(14, bndB, 0)
        STORE_BLK(127)                      // slots 14,15 unused by consumers
        asm volatile("" ::: "memory");
        if (lane == 0) *mflag = 128;
    }
#undef CTC_STEP
#undef RUN_BLOCK
#undef LOAD_BLK
#undef STORE_BLK

    // loss: states 399 (wave3 lane7 al1) and 400 (wave3 lane8 al0)
    const float A = __shfl(al1, 7, 64);
    const float B = __shfl(al0, 8, 64);
    if (wid == 3 && lane == 0) {
        const float m  = fmaxf(A, B);
        const float ls = m + __builtin_amdgcn_logf(
            __builtin_amdgcn_exp2f(A - m) + __builtin_amdgcn_exp2f(B - m));
        loss_ws[n] = -ls * K_LN2;   // back to natural log
    }
}

__global__ void ctc_reduce(const float* __restrict__ ws, float* __restrict__ out)
{
    const int tid = threadIdx.x;   // 256 threads, 4 waves
    float v = ws[tid];
    v += __shfl_down(v, 32);
    v += __shfl_down(v, 16);
    v += __shfl_down(v, 8);
    v += __shfl_down(v, 4);
    v += __shfl_down(v, 2);
    v += __shfl_down(v, 1);
    __shared__ float p[4];
    if ((tid & 63) == 0) p[tid >> 6] = v;
    __syncthreads();
    if (tid == 0) out[0] = (p[0] + p[1]) + (p[2] + p[3]);
}

extern "C" void kernel_launch(void* const* d_in, const int* in_sizes, int n_in,
                              void* d_out, int out_size, void* d_ws, size_t ws_size,
                              hipStream_t stream)
{
    const float* pred   = (const float*)d_in[0];
    const int*   target = (const int*)d_in[1];
    // d_in[2] = input_length: unused by the reference computation
    const int*   tlen   = (const int*)d_in[3];
    float* ws = (float*)d_ws;

    ctc_alpha<<<NN, 256, 0, stream>>>(pred, target, tlen, ws);
    ctc_reduce<<<1, NN, 0, stream>>>(ws, (float*)d_out);
}